// Round 9
// baseline (313.145 us; speedup 1.0000x reference)
//
#include <hip/hip_runtime.h>

#define NROWS 16384
#define DIM   1024
#define QSCALE 32.0f            // fp4 pre-scale 2^5
#define E8M0S  0x7A7A7A7Au      // 122 -> 2^-5 in every byte (both operands)

typedef int    v4i    __attribute__((ext_vector_type(4)));
typedef int    v8i    __attribute__((ext_vector_type(8)));
typedef float  f32x16 __attribute__((ext_vector_type(16)));

__device__ __forceinline__ void glds16(const void* g, void* l) {
    __builtin_amdgcn_global_load_lds(
        (const __attribute__((address_space(1))) void*)g,
        (__attribute__((address_space(3))) void*)l,
        16, 0, 0);
}

__device__ __forceinline__ float fexp2(float x) {
#if __has_builtin(__builtin_amdgcn_exp2f)
    return __builtin_amdgcn_exp2f(x);
#else
    return exp2f(x);
#endif
}
__device__ __forceinline__ float flog2(float x) {
#if __has_builtin(__builtin_amdgcn_logf)
    return __builtin_amdgcn_logf(x);
#else
    return log2f(x);
#endif
}

// fp4 e2m1 round-to-nearest encode of y (|y| clipped to 6).
__device__ __forceinline__ unsigned fp4_nib(float y) {
    unsigned s = (__float_as_uint(y) >> 31) << 3;
    float a = fminf(fabsf(y), 6.0f);
    unsigned c = (unsigned)(a >= 0.25f) + (unsigned)(a >= 0.75f) +
                 (unsigned)(a >= 1.25f) + (unsigned)(a >= 1.75f) +
                 (unsigned)(a >= 2.5f)  + (unsigned)(a >= 3.5f)  +
                 (unsigned)(a >= 5.0f);
    return c | s;
}

// FRAGMENT-NATIVE quantized layout (R9): Q[g][c][r][16B], offset =
// ((g*32 + c)*32 + r)*16, where g=row>>5, r=row&31, c=k-chunk (32 fp4
// elems = 16B). An MFMA fragment (32 rows x 2 chunks) is 1 KB CONTIGUOUS:
// lane l reads +l*16. Kills all LDS swizzling and makes B loadable
// L2->reg directly.
//
// norm_fused: 2 rows per wave (half-wave owns a row; 32-lane reductions).
// Lane r31 covers elements [r31*32, r31*32+32) of its row = exactly one
// 16B output chunk -> one v4i store per matrix.
__global__ __launch_bounds__(256) void norm_fused(
    const float* __restrict__ img,
    const float* __restrict__ txt,
    unsigned char* __restrict__ imgQ,   // [512][32][32][16] packed fp4
    unsigned char* __restrict__ txtQ,
    const float* __restrict__ lscale,
    const float* __restrict__ lbias,
    float* __restrict__ diagPart) {
    const int t    = threadIdx.x;
    const int lane = t & 63;
    const int r31  = lane & 31;
    const int half = lane >> 5;
    const int gw   = blockIdx.x * 4 + (t >> 6);   // 8192 waves x 2 rows
    const int row  = gw * 2 + half;
    const float sc   = __expf(lscale[0]);
    const float bias = lbias[0];

    // lane loads 32 consecutive elems (8 float4) of its row; the 128B line
    // per lane is fetched once and L1-served across the 8 loads.
    const float4* pi = (const float4*)(img + (size_t)row * DIM) + r31 * 8;
    const float4* pt = (const float4*)(txt + (size_t)row * DIM) + r31 * 8;
    float4 vi[8], vt[8];
    float ssi = 0.0f, sst = 0.0f, dot = 0.0f;
    #pragma unroll
    for (int j = 0; j < 8; ++j) {
        vi[j] = pi[j];
        vt[j] = pt[j];
        ssi += vi[j].x*vi[j].x + vi[j].y*vi[j].y + vi[j].z*vi[j].z + vi[j].w*vi[j].w;
        sst += vt[j].x*vt[j].x + vt[j].y*vt[j].y + vt[j].z*vt[j].z + vt[j].w*vt[j].w;
        dot += vi[j].x*vt[j].x + vi[j].y*vt[j].y + vi[j].z*vt[j].z + vi[j].w*vt[j].w;
    }
    #pragma unroll
    for (int off = 1; off < 32; off <<= 1) {   // half-wave (per-row) reduce
        ssi += __shfl_xor(ssi, off, 64);
        sst += __shfl_xor(sst, off, 64);
        dot += __shfl_xor(dot, off, 64);
    }
    const float ii = 1.0f / fmaxf(sqrtf(ssi), 1e-12f);
    const float it = 1.0f / fmaxf(sqrtf(sst), 1e-12f);
    if (r31 == 0) diagPart[row] = -fmaf(sc, dot * ii * it, bias);

    const float qi = ii * QSCALE, qt = it * QSCALE;
    unsigned wp[4] = {0, 0, 0, 0}, wq[4] = {0, 0, 0, 0};
    #pragma unroll
    for (int j = 0; j < 8; ++j) {
        unsigned p = fp4_nib(vi[j].x * qi)       | (fp4_nib(vi[j].y * qi) << 4) |
                     (fp4_nib(vi[j].z * qi) << 8) | (fp4_nib(vi[j].w * qi) << 12);
        unsigned q = fp4_nib(vt[j].x * qt)       | (fp4_nib(vt[j].y * qt) << 4) |
                     (fp4_nib(vt[j].z * qt) << 8) | (fp4_nib(vt[j].w * qt) << 12);
        wp[j >> 1] |= p << ((j & 1) * 16);
        wq[j >> 1] |= q << ((j & 1) * 16);
    }
    const size_t qoff = ((size_t)(row >> 5) * 32 + r31) * 512 + (row & 31) * 16;
    *(v4i*)(imgQ + qoff) = *(v4i*)wp;
    *(v4i*)(txtQ + qoff) = *(v4i*)wq;
}

// MX-fp4 GEMM, R9: A staged in LDS (fragment-linear, swizzle-free,
// conflict-free canonical reads); B read DIRECTLY L2->reg (fragment = 1KB
// contiguous coalesced load; XCD-resident band via T1 map). LDS traffic
// HALVES vs R8 (R8 counters: LDS pipe ~110us busy > matrix 60us floor).
// 128x128 block tile, 4 waves 2x2 (64x64 wave tile, acc[2][2]=64 AGPR),
// LDS 32.5 KB dbuf, __launch_bounds__(256,4) -> 4 independent blocks/CU.
// B pipelined 1 slice ahead in source; compiler-managed waits; ONE
// __syncthreads per K-tile (its vmcnt(0) drain gates the glds staging).
__global__ __launch_bounds__(256, 4) void siglip_gemm(
    const unsigned char* __restrict__ A,
    const unsigned char* __restrict__ B,
    const float* __restrict__ lscale,
    const float* __restrict__ lbias,
    float* __restrict__ gemmPart)
{
    __shared__ unsigned char sA[2][16 * 1024];  // [buf][(g_local*8 + c_local)*512]
    __shared__ float wred[4];

    const int t    = threadIdx.x;
    const int lane = t & 63;
    const int wave = t >> 6;        // 0..3
    const int wr   = wave >> 1;     // 0..1 : A half (64 rows)
    const int wc   = wave & 1;      // 0..1 : B half (64 cols)

    // T1 XCD-bijective map: 16384 blocks = 8 xcd x 2048 lb. Each XCD owns a
    // 16-bcol B band (1MB, L2-resident); 16 consecutive lb share brow.
    const int b    = blockIdx.x;
    const int xcd  = b & 7;
    const int lb   = b >> 3;               // 0..2047
    const int bcol = xcd * 16 + (lb & 15); // 0..127
    const int brow = lb >> 4;              // 0..127

    // Per-lane fragment bases (+lane*16 inside a 1KB fragment-pair).
    // A: group gA = brow*4 + g_local; staged by wave w for g_local = w.
    const unsigned char* Aw = A + ((size_t)(brow * 4 + wave) * 32) * 512
                                + (size_t)lane * 16;
    // B: group gB = bcol*4 + wc*2 + i; read direct to regs.
    const unsigned char* Bw = B + ((size_t)(bcol * 4 + wc * 2) * 32) * 512
                                + (size_t)lane * 16;

    f32x16 acc[2][2] = {};

    // ---- prologue: stage A K-tile 0 into buf 0 ----
    #pragma unroll
    for (int s = 0; s < 4; ++s)
        glds16(Aw + (size_t)(s * 2) * 512, sA[0] + (wave * 8 + s * 2) * 512);
    __syncthreads();

    #pragma unroll
    for (int k = 0; k < 4; ++k) {
        const int cur = k & 1;

        // ---- issue next A K-tile staging into other buffer ----
        if (k < 3) {
            #pragma unroll
            for (int s = 0; s < 4; ++s)
                glds16(Aw + (size_t)((k + 1) * 8 + s * 2) * 512,
                       sA[cur ^ 1] + (wave * 8 + s * 2) * 512);
        }

        // ---- B slice 0 (direct L2->reg, 1KB coalesced each) ----
        v4i bc0 = *(const v4i*)(Bw + (size_t)(k * 8) * 512);
        v4i bc1 = *(const v4i*)(Bw + 16384 + (size_t)(k * 8) * 512);

        #pragma unroll
        for (int ks = 0; ks < 4; ++ks) {
            v4i bn0, bn1;
            if (ks < 3) {   // prefetch next slice's B under this slice's MFMAs
                bn0 = *(const v4i*)(Bw + (size_t)(k * 8 + (ks + 1) * 2) * 512);
                bn1 = *(const v4i*)(Bw + 16384 + (size_t)(k * 8 + (ks + 1) * 2) * 512);
            }
            // A fragments: canonical contiguous wave read, conflict-free
            v4i a0 = *(const v4i*)(sA[cur] + ((2 * wr + 0) * 8 + ks * 2) * 512 + lane * 16);
            v4i a1 = *(const v4i*)(sA[cur] + ((2 * wr + 1) * 8 + ks * 2) * 512 + lane * 16);

            v8i A0 = __builtin_shufflevector(a0, a0, 0, 1, 2, 3, -1, -1, -1, -1);
            v8i A1 = __builtin_shufflevector(a1, a1, 0, 1, 2, 3, -1, -1, -1, -1);
            v8i B0 = __builtin_shufflevector(bc0, bc0, 0, 1, 2, 3, -1, -1, -1, -1);
            v8i B1 = __builtin_shufflevector(bc1, bc1, 0, 1, 2, 3, -1, -1, -1, -1);

            __builtin_amdgcn_s_setprio(1);
            acc[0][0] = __builtin_amdgcn_mfma_scale_f32_32x32x64_f8f6f4(
                A0, B0, acc[0][0], 4, 4, 0, (int)E8M0S, 0, (int)E8M0S);
            acc[0][1] = __builtin_amdgcn_mfma_scale_f32_32x32x64_f8f6f4(
                A0, B1, acc[0][1], 4, 4, 0, (int)E8M0S, 0, (int)E8M0S);
            acc[1][0] = __builtin_amdgcn_mfma_scale_f32_32x32x64_f8f6f4(
                A1, B0, acc[1][0], 4, 4, 0, (int)E8M0S, 0, (int)E8M0S);
            acc[1][1] = __builtin_amdgcn_mfma_scale_f32_32x32x64_f8f6f4(
                A1, B1, acc[1][1], 4, 4, 0, (int)E8M0S, 0, (int)E8M0S);
            __builtin_amdgcn_s_setprio(0);

            if (ks < 3) { bc0 = bn0; bc1 = bn1; }
        }

        // ---- tile gate: drains glds (vmcnt) + swaps buffers ----
        __syncthreads();
    }

    // Epilogue: softplus(z) over all elements (label=-1 form); diagonal fixed
    // by -z_ii (diagPart). Group-of-4 log trick (4-term product < 2^125: safe).
    const float l2e   = 1.44269504088896341f;
    const float scale = __expf(lscale[0]);
    const float aCo   = scale * l2e;
    const float bCo   = lbias[0] * l2e;
    float local = 0.0f;
    #pragma unroll
    for (int mi = 0; mi < 2; ++mi)
        #pragma unroll
        for (int ni = 0; ni < 2; ++ni)
            #pragma unroll
            for (int r = 0; r < 16; r += 4) {
                float e0 = fexp2(fmaf(aCo, acc[mi][ni][r + 0], bCo));
                float e1 = fexp2(fmaf(aCo, acc[mi][ni][r + 1], bCo));
                float e2 = fexp2(fmaf(aCo, acc[mi][ni][r + 2], bCo));
                float e3 = fexp2(fmaf(aCo, acc[mi][ni][r + 3], bCo));
                float p  = ((1.0f + e0) * (1.0f + e1)) *
                           ((1.0f + e2) * (1.0f + e3));
                local += flog2(p);
            }

    #pragma unroll
    for (int off = 32; off > 0; off >>= 1) local += __shfl_down(local, off, 64);
    if (lane == 0) wred[wave] = local;
    __syncthreads();
    if (t == 0)
        gemmPart[blockIdx.x] =
            (wred[0] + wred[1] + wred[2] + wred[3]) * 0.69314718055994531f;
}

// Sum 32768 partials (diagPart 16384 ++ gemmPart 16384, contiguous) -> loss.
__global__ __launch_bounds__(1024) void finalize_kernel(
    const float* __restrict__ parts, float* __restrict__ out) {
    __shared__ float wr[16];
    const int t    = threadIdx.x;
    const int lane = t & 63;
    const int wave = t >> 6;
    const float4* p4 = (const float4*)parts;   // 8192 float4
    float s = 0.0f;
    for (int i = t; i < 8192; i += 1024) {
        float4 v = p4[i];
        s += v.x + v.y + v.z + v.w;
    }
    #pragma unroll
    for (int off = 32; off > 0; off >>= 1) s += __shfl_down(s, off, 64);
    if (lane == 0) wr[wave] = s;
    __syncthreads();
    if (t == 0) {
        float tot = 0.0f;
        #pragma unroll
        for (int i = 0; i < 16; ++i) tot += wr[i];
        out[0] = tot / 268435456.0f;   // / N^2
    }
}

extern "C" void kernel_launch(void* const* d_in, const int* in_sizes, int n_in,
                              void* d_out, int out_size, void* d_ws, size_t ws_size,
                              hipStream_t stream) {
    const float* img    = (const float*)d_in[0];
    const float* txt    = (const float*)d_in[1];
    const float* lscale = (const float*)d_in[2];
    const float* lbias  = (const float*)d_in[3];
    float* out = (float*)d_out;

    char* ws = (char*)d_ws;
    unsigned char* imgQ = (unsigned char*)ws;                          // 8 MB
    unsigned char* txtQ = (unsigned char*)(ws + (size_t)NROWS * 512);  // 8 MB
    float* parts   = (float*)(ws + (size_t)2 * NROWS * 512);           // 32768 floats
    float* diagPart = parts;
    float* gemmPart = parts + NROWS;

    norm_fused<<<2048, 256, 0, stream>>>(img, txt, imgQ, txtQ, lscale, lbias, diagPart);
    siglip_gemm<<<dim3((NROWS / 128) * (NROWS / 128)), 256, 0, stream>>>(
        imgQ, txtQ, lscale, lbias, gemmPart);
    finalize_kernel<<<1, 1024, 0, stream>>>(parts, out);
}

// Round 10
// 310.103 us; speedup vs baseline: 1.0098x; 1.0098x over previous
//
#include <hip/hip_runtime.h>

#define NROWS 16384
#define DIM   1024
#define QSCALE 32.0f            // fp4 pre-scale 2^5
#define E8M0S  0x7A7A7A7Au      // 122 -> 2^-5 in every byte (both operands)

typedef int    v4i    __attribute__((ext_vector_type(4)));
typedef int    v8i    __attribute__((ext_vector_type(8)));
typedef float  f32x16 __attribute__((ext_vector_type(16)));

__device__ __forceinline__ float fexp2(float x) {
#if __has_builtin(__builtin_amdgcn_exp2f)
    return __builtin_amdgcn_exp2f(x);
#else
    return exp2f(x);
#endif
}
__device__ __forceinline__ float flog2(float x) {
#if __has_builtin(__builtin_amdgcn_logf)
    return __builtin_amdgcn_logf(x);
#else
    return log2f(x);
#endif
}

// fp4 e2m1 round-to-nearest encode of y (|y| clipped to 6).
__device__ __forceinline__ unsigned fp4_nib(float y) {
    unsigned s = (__float_as_uint(y) >> 31) << 3;
    float a = fminf(fabsf(y), 6.0f);
    unsigned c = (unsigned)(a >= 0.25f) + (unsigned)(a >= 0.75f) +
                 (unsigned)(a >= 1.25f) + (unsigned)(a >= 1.75f) +
                 (unsigned)(a >= 2.5f)  + (unsigned)(a >= 3.5f)  +
                 (unsigned)(a >= 5.0f);
    return c | s;
}

// FRAGMENT-NATIVE quantized layout: Q[g][c][r][16B], offset =
// ((g*32 + c)*32 + r)*16, g=row>>5, r=row&31, c=k-chunk (32 fp4 = 16B).
// An MFMA fragment (32 rows x 64 k) is 1 KB CONTIGUOUS: lane l at +l*16
// (since (l>>5)*512 + (l&31)*16 == l*16). Any fragment = one coalesced
// dwordx4 L2->reg load. This enables the R10 zero-LDS GEMM.
__global__ __launch_bounds__(256) void norm_fused(
    const float* __restrict__ img,
    const float* __restrict__ txt,
    unsigned char* __restrict__ imgQ,   // [512][32][32][16] packed fp4
    unsigned char* __restrict__ txtQ,
    const float* __restrict__ lscale,
    const float* __restrict__ lbias,
    float* __restrict__ diagPart) {
    const int t    = threadIdx.x;
    const int lane = t & 63;
    const int r31  = lane & 31;
    const int half = lane >> 5;
    const int gw   = blockIdx.x * 4 + (t >> 6);   // 8192 waves x 2 rows
    const int row  = gw * 2 + half;
    const float sc   = __expf(lscale[0]);
    const float bias = lbias[0];

    const float4* pi = (const float4*)(img + (size_t)row * DIM) + r31 * 8;
    const float4* pt = (const float4*)(txt + (size_t)row * DIM) + r31 * 8;
    float4 vi[8], vt[8];
    float ssi = 0.0f, sst = 0.0f, dot = 0.0f;
    #pragma unroll
    for (int j = 0; j < 8; ++j) {
        vi[j] = pi[j];
        vt[j] = pt[j];
        ssi += vi[j].x*vi[j].x + vi[j].y*vi[j].y + vi[j].z*vi[j].z + vi[j].w*vi[j].w;
        sst += vt[j].x*vt[j].x + vt[j].y*vt[j].y + vt[j].z*vt[j].z + vt[j].w*vt[j].w;
        dot += vi[j].x*vt[j].x + vi[j].y*vt[j].y + vi[j].z*vt[j].z + vi[j].w*vt[j].w;
    }
    #pragma unroll
    for (int off = 1; off < 32; off <<= 1) {   // half-wave (per-row) reduce
        ssi += __shfl_xor(ssi, off, 64);
        sst += __shfl_xor(sst, off, 64);
        dot += __shfl_xor(dot, off, 64);
    }
    const float ii = 1.0f / fmaxf(sqrtf(ssi), 1e-12f);
    const float it = 1.0f / fmaxf(sqrtf(sst), 1e-12f);
    if (r31 == 0) diagPart[row] = -fmaf(sc, dot * ii * it, bias);

    const float qi = ii * QSCALE, qt = it * QSCALE;
    unsigned wp[4] = {0, 0, 0, 0}, wq[4] = {0, 0, 0, 0};
    #pragma unroll
    for (int j = 0; j < 8; ++j) {
        unsigned p = fp4_nib(vi[j].x * qi)       | (fp4_nib(vi[j].y * qi) << 4) |
                     (fp4_nib(vi[j].z * qi) << 8) | (fp4_nib(vi[j].w * qi) << 12);
        unsigned q = fp4_nib(vt[j].x * qt)       | (fp4_nib(vt[j].y * qt) << 4) |
                     (fp4_nib(vt[j].z * qt) << 8) | (fp4_nib(vt[j].w * qt) << 12);
        wp[j >> 1] |= p << ((j & 1) * 16);
        wq[j >> 1] |= q << ((j & 1) * 16);
    }
    const size_t qoff = ((size_t)(row >> 5) * 32 + r31) * 512 + (row & 31) * 16;
    *(v4i*)(imgQ + qoff) = *(v4i*)wp;
    *(v4i*)(txtQ + qoff) = *(v4i*)wq;
}

// MX-fp4 GEMM, R10: ZERO-LDS, ZERO-BARRIER, fully wave-independent.
// Nine LDS-staged variants (R2-R9: monolithic/phased/counted/persistent/
// small-block/B-direct) all plateau 170-195us, 30-37% MfmaUtil; pipe-work
// arithmetic (matrix 60us, LDS ~40us @256B/clk, VMEM ~50us) says nothing
// is bandwidth-bound -> the invariant cost is the LDS round-trip + block
// barrier coupling itself. R10 removes both: each wave computes an
// independent 64x64 output tile; A and B fragments (1KB contiguous in the
// fragment-native layout) are loaded L2->reg directly (one dwordx4/lane),
// depth-1 prefetch (load slice s+1 under slice s's 4 MFMAs; compiler
// emits counted vmcnt on the register deps). 4 waves/block as 2x2 over
// 128x128 for L1 fragment sharing; no __syncthreads until the final
// 16-byte reduce. acc 64 + operands 32 + addr ~16 => ~112 regs,
// __launch_bounds__(256,4) -> 4 waves/SIMD.
// T1 XCD-banding unchanged (B band 1MB L2-resident; FETCH held at 37MB).
__global__ __launch_bounds__(256, 4) void siglip_gemm(
    const unsigned char* __restrict__ A,
    const unsigned char* __restrict__ B,
    const float* __restrict__ lscale,
    const float* __restrict__ lbias,
    float* __restrict__ gemmPart)
{
    __shared__ float wred[4];

    const int t    = threadIdx.x;
    const int lane = t & 63;
    const int wave = t >> 6;        // 0..3
    const int wy   = wave >> 1;     // 0..1 : A half (64 rows)
    const int wx   = wave & 1;      // 0..1 : B half (64 cols)

    // T1 XCD-bijective map: 16384 blocks = 8 xcd x 2048 lb. Each XCD owns a
    // 16-bcol B band (1MB, L2-resident); 16 consecutive lb share brow.
    const int b    = blockIdx.x;
    const int xcd  = b & 7;
    const int lb   = b >> 3;               // 0..2047
    const int bcol = xcd * 16 + (lb & 15); // 0..127
    const int brow = lb >> 4;              // 0..127

    // Fragment stream bases (group stride = 32 chunks * 512B = 16 KB).
    // Wave's A rows: groups brow*4 + wy*2 + {0,1}; B cols: bcol*4 + wx*2 + {0,1}.
    const unsigned char* Ab = A + (size_t)(brow * 4 + wy * 2) * 16384
                                + (size_t)lane * 16;
    const unsigned char* Bb = B + (size_t)(bcol * 4 + wx * 2) * 16384
                                + (size_t)lane * 16;

    f32x16 acc[2][2] = {};

    // slice s (K=64): fragment at +s*1024; second group at +16384.
    v4i a0 = *(const v4i*)(Ab);
    v4i a1 = *(const v4i*)(Ab + 16384);
    v4i b0 = *(const v4i*)(Bb);
    v4i b1 = *(const v4i*)(Bb + 16384);

    #pragma unroll
    for (int s = 0; s < 16; ++s) {
        v4i na0, na1, nb0, nb1;
        if (s < 15) {   // depth-1 prefetch: loads for s+1 fly under s's MFMAs
            const int o = (s + 1) * 1024;
            na0 = *(const v4i*)(Ab + o);
            na1 = *(const v4i*)(Ab + 16384 + o);
            nb0 = *(const v4i*)(Bb + o);
            nb1 = *(const v4i*)(Bb + 16384 + o);
        }

        v8i A0 = __builtin_shufflevector(a0, a0, 0, 1, 2, 3, -1, -1, -1, -1);
        v8i A1 = __builtin_shufflevector(a1, a1, 0, 1, 2, 3, -1, -1, -1, -1);
        v8i B0 = __builtin_shufflevector(b0, b0, 0, 1, 2, 3, -1, -1, -1, -1);
        v8i B1 = __builtin_shufflevector(b1, b1, 0, 1, 2, 3, -1, -1, -1, -1);

        __builtin_amdgcn_s_setprio(1);
        acc[0][0] = __builtin_amdgcn_mfma_scale_f32_32x32x64_f8f6f4(
            A0, B0, acc[0][0], 4, 4, 0, (int)E8M0S, 0, (int)E8M0S);
        acc[0][1] = __builtin_amdgcn_mfma_scale_f32_32x32x64_f8f6f4(
            A0, B1, acc[0][1], 4, 4, 0, (int)E8M0S, 0, (int)E8M0S);
        acc[1][0] = __builtin_amdgcn_mfma_scale_f32_32x32x64_f8f6f4(
            A1, B0, acc[1][0], 4, 4, 0, (int)E8M0S, 0, (int)E8M0S);
        acc[1][1] = __builtin_amdgcn_mfma_scale_f32_32x32x64_f8f6f4(
            A1, B1, acc[1][1], 4, 4, 0, (int)E8M0S, 0, (int)E8M0S);
        __builtin_amdgcn_s_setprio(0);

        if (s < 15) { a0 = na0; a1 = na1; b0 = nb0; b1 = nb1; }
    }

    // Epilogue: softplus(z) over all elements (label=-1 form); diagonal fixed
    // by -z_ii (diagPart). Group-of-4 log trick (4-term product < 2^125: safe).
    const float l2e   = 1.44269504088896341f;
    const float scale = __expf(lscale[0]);
    const float aCo   = scale * l2e;
    const float bCo   = lbias[0] * l2e;
    float local = 0.0f;
    #pragma unroll
    for (int mi = 0; mi < 2; ++mi)
        #pragma unroll
        for (int ni = 0; ni < 2; ++ni)
            #pragma unroll
            for (int r = 0; r < 16; r += 4) {
                float e0 = fexp2(fmaf(aCo, acc[mi][ni][r + 0], bCo));
                float e1 = fexp2(fmaf(aCo, acc[mi][ni][r + 1], bCo));
                float e2 = fexp2(fmaf(aCo, acc[mi][ni][r + 2], bCo));
                float e3 = fexp2(fmaf(aCo, acc[mi][ni][r + 3], bCo));
                float p  = ((1.0f + e0) * (1.0f + e1)) *
                           ((1.0f + e2) * (1.0f + e3));
                local += flog2(p);
            }

    #pragma unroll
    for (int off = 32; off > 0; off >>= 1) local += __shfl_down(local, off, 64);
    if (lane == 0) wred[wave] = local;
    __syncthreads();
    if (t == 0)
        gemmPart[blockIdx.x] =
            (wred[0] + wred[1] + wred[2] + wred[3]) * 0.69314718055994531f;
}

// Sum 32768 partials (diagPart 16384 ++ gemmPart 16384, contiguous) -> loss.
__global__ __launch_bounds__(1024) void finalize_kernel(
    const float* __restrict__ parts, float* __restrict__ out) {
    __shared__ float wr[16];
    const int t    = threadIdx.x;
    const int lane = t & 63;
    const int wave = t >> 6;
    const float4* p4 = (const float4*)parts;   // 8192 float4
    float s = 0.0f;
    for (int i = t; i < 8192; i += 1024) {
        float4 v = p4[i];
        s += v.x + v.y + v.z + v.w;
    }
    #pragma unroll
    for (int off = 32; off > 0; off >>= 1) s += __shfl_down(s, off, 64);
    if (lane == 0) wr[wave] = s;
    __syncthreads();
    if (t == 0) {
        float tot = 0.0f;
        #pragma unroll
        for (int i = 0; i < 16; ++i) tot += wr[i];
        out[0] = tot / 268435456.0f;   // / N^2
    }
}

extern "C" void kernel_launch(void* const* d_in, const int* in_sizes, int n_in,
                              void* d_out, int out_size, void* d_ws, size_t ws_size,
                              hipStream_t stream) {
    const float* img    = (const float*)d_in[0];
    const float* txt    = (const float*)d_in[1];
    const float* lscale = (const float*)d_in[2];
    const float* lbias  = (const float*)d_in[3];
    float* out = (float*)d_out;

    char* ws = (char*)d_ws;
    unsigned char* imgQ = (unsigned char*)ws;                          // 8 MB
    unsigned char* txtQ = (unsigned char*)(ws + (size_t)NROWS * 512);  // 8 MB
    float* parts   = (float*)(ws + (size_t)2 * NROWS * 512);           // 32768 floats
    float* diagPart = parts;
    float* gemmPart = parts + NROWS;

    norm_fused<<<2048, 256, 0, stream>>>(img, txt, imgQ, txtQ, lscale, lbias, diagPart);
    siglip_gemm<<<dim3((NROWS / 128) * (NROWS / 128)), 256, 0, stream>>>(
        imgQ, txtQ, lscale, lbias, gemmPart);
    finalize_kernel<<<1, 1024, 0, stream>>>(parts, out);
}